// Round 9
// baseline (117.970 us; speedup 1.0000x reference)
//
#include <hip/hip_runtime.h>
#include <math.h>

#define DN  768
#define NC  53
#define NCP 64         // classes padded for MFMA
#define NKS 24         // K steps of 32
#define MB  128        // rows per block (32/wave)
#define WR  32         // rows per wave
#define YTS 66         // LDS yt row stride (floats)

typedef __attribute__((ext_vector_type(8))) __bf16 bf16x8;
typedef __attribute__((ext_vector_type(8))) short short8v;
typedef __attribute__((ext_vector_type(4))) float f32x4;

// f32 -> bf16 bits, round-to-nearest-even (prep/epilogue only)
static __device__ __forceinline__ unsigned short f2bf(float f) {
    unsigned int u = __builtin_bit_cast(unsigned int, f);
    u = (u + 0x7FFFu + ((u >> 16) & 1u)) >> 16;
    return (unsigned short)u;
}
static __device__ __forceinline__ float bf2f(unsigned short h) {
    unsigned int u = ((unsigned int)h) << 16;
    return __builtin_bit_cast(float, u);
}

// ---- k0 (merged): blocks 0..191 -> wb fragment-major; 192.. -> offs ---------
__global__ void prep_kernel(const float* __restrict__ w,
                            const int*   __restrict__ seg,
                            unsigned short* __restrict__ wb,
                            int* __restrict__ offs,
                            int N, int B) {
    const int bid = blockIdx.x;
    if (bid < 192) {
        int i = bid * 256 + threadIdx.x;          // covers NKS*4*64*8 = 49152
        const int e    = i & 7;
        const int lane = (i >> 3) & 63;
        const int ct   = (i >> 9) & 3;
        const int ks   = i >> 11;
        const int cls  = ct * 16 + (lane & 15);
        const int k    = ks * 32 + ((lane >> 4) << 3) + e;
        wb[i] = (cls < NC) ? f2bf(w[cls * DN + k]) : (unsigned short)0;
    } else {
        int i = (bid - 192) * 256 + threadIdx.x;
        if (i >= N) return;
        int cur  = seg[i];
        int prev = (i == 0) ? -1 : seg[i - 1];
        for (int b = prev + 1; b <= cur; ++b) offs[b] = i;
        if (i == N - 1)
            for (int b = cur + 1; b <= B; ++b) offs[b] = N;
    }
}

// ---- k1: Y_bf16[N][64] = bf16(X) @ bf16(W)^T; att[j] = Y[j][label[j]] -------
// wave = 32 rows x 64 cols; 2-deep register double-buffer; no barriers.
#define ISSUE(buf, ks)                                                          \
    {                                                                           \
        _Pragma("unroll")                                                       \
        for (int f = 0; f < 2; ++f) {                                           \
            const unsigned ao = aoff + f * (16u * DN) + (unsigned)((ks) * 32);  \
            la[buf][f * 2]     = *(const float4*)(xb + ao);                     \
            la[buf][f * 2 + 1] = *(const float4*)(xb + ao + 4);                 \
        }                                                                       \
        _Pragma("unroll")                                                       \
        for (int ct = 0; ct < 4; ++ct)                                          \
            lb[buf][ct] = *(const short8v*)(wb + (((ks) * 4 + ct) * 64 + lane) * 8); \
    }

__global__ __launch_bounds__(256, 4) void gemm_y4(
    const float* __restrict__ x,
    const int*   __restrict__ label,
    const unsigned short* __restrict__ wb,
    unsigned short* __restrict__ yb,   // [N][64] bf16
    float* __restrict__ att)           // [N]
{
    __shared__ float yt[4][WR * YTS];  // 33792 B

    const int lane = threadIdx.x & 63;
    const int wv   = threadIdx.x >> 6;
    const int r16  = lane & 15;
    const int kg   = lane >> 4;
    const long row0 = (long)blockIdx.x * MB + wv * WR;

    f32x4 acc[2][4];
    #pragma unroll
    for (int f = 0; f < 2; ++f)
        #pragma unroll
        for (int ct = 0; ct < 4; ++ct)
            acc[f][ct] = (f32x4){0.f, 0.f, 0.f, 0.f};

    const float* xb = x + row0 * DN;                 // wave-uniform base
    const unsigned aoff = (unsigned)(r16 * DN + kg * 8);

    float4  la[2][4];
    short8v lb[2][4];
    ISSUE(0, 0)

    #pragma unroll
    for (int ks = 0; ks < NKS; ++ks) {
        const int cur = ks & 1, nxt = cur ^ 1;
        if (ks + 1 < NKS) ISSUE(nxt, ks + 1)         // issue next BEFORE using cur

        bf16x8 a8[2];
        #pragma unroll
        for (int f = 0; f < 2; ++f) {
            const float4 u0 = la[cur][f * 2], u1 = la[cur][f * 2 + 1];
            bf16x8 t;
            t[0] = (__bf16)u0.x; t[1] = (__bf16)u0.y;
            t[2] = (__bf16)u0.z; t[3] = (__bf16)u0.w;
            t[4] = (__bf16)u1.x; t[5] = (__bf16)u1.y;
            t[6] = (__bf16)u1.z; t[7] = (__bf16)u1.w;
            a8[f] = t;
        }
        #pragma unroll
        for (int ct = 0; ct < 4; ++ct)
            #pragma unroll
            for (int f = 0; f < 2; ++f)
                acc[f][ct] = __builtin_amdgcn_mfma_f32_16x16x32_bf16(
                    a8[f], __builtin_bit_cast(bf16x8, lb[cur][ct]), acc[f][ct], 0, 0, 0);
    }

    // Epilogue. C/D: col = ct*16 + r16 (class), row = f*16 + kg*4 + r.
    float* myt = yt[wv];
    #pragma unroll
    for (int f = 0; f < 2; ++f)
        #pragma unroll
        for (int ct = 0; ct < 4; ++ct) {
            const int rl = f * 16 + kg * 4;
            #pragma unroll
            for (int r = 0; r < 4; ++r) {
                const float v = acc[f][ct][r];
                myt[(rl + r) * YTS + ct * 16 + r16] = v;
                yb[(row0 + rl + r) * NCP + ct * 16 + r16] = f2bf(v);
            }
        }
    // same-wave LDS RAW: compiler inserts lgkmcnt wait; no barrier needed
    if (lane < WR) {
        const long grow = row0 + lane;               // lane <-> local row
        const int  lab  = label[grow];               // coalesced
        att[grow] = myt[lane * YTS + lab];           // LDS gather
    }
}

// ---- k2: per-bag softmax pooling: att coalesced + bf16 y rows ---------------
__global__ __launch_bounds__(256) void pool_kernel(
    const unsigned short* __restrict__ yb,
    const float* __restrict__ att,
    const int*   __restrict__ offs,
    const float* __restrict__ bias,
    float*       __restrict__ out,
    int Btot)
{
    __shared__ float s_e[4][64];
    const int wv   = threadIdx.x >> 6;
    const int lane = threadIdx.x & 63;
    const int bag  = blockIdx.x * 4 + wv;
    if (bag >= Btot) return;
    const int s = offs[bag], e = offs[bag + 1];

    float m = -INFINITY, den = 0.f, facc = 0.f;
    for (int j0 = s; j0 < e; j0 += 64) {
        const int j = j0 + lane;
        float a = (j < e) ? att[j] : -INFINITY;          // coalesced stream
        float cm = a;
        #pragma unroll
        for (int off = 1; off < 64; off <<= 1) cm = fmaxf(cm, __shfl_xor(cm, off));
        const float nm = fmaxf(m, cm);
        const float sc = __expf(m - nm);                 // first iter: exp(-inf)=0
        const float ej = (j < e) ? __expf(a - nm) : 0.f;
        float cd = ej;
        #pragma unroll
        for (int off = 1; off < 64; off <<= 1) cd += __shfl_xor(cd, off);
        den = den * sc + cd;
        s_e[wv][lane] = ej;                              // same-wave LDS broadcast
        const int cnt = min(64, e - j0);
        float f0 = 0.f, f1 = 0.f, f2 = 0.f, f3 = 0.f;
        int t = 0;
        for (; t + 4 <= cnt; t += 4) {                   // 4 chains break FMA dep
            f0 += s_e[wv][t]     * bf2f(yb[(size_t)(j0 + t)     * NCP + lane]);
            f1 += s_e[wv][t + 1] * bf2f(yb[(size_t)(j0 + t + 1) * NCP + lane]);
            f2 += s_e[wv][t + 2] * bf2f(yb[(size_t)(j0 + t + 2) * NCP + lane]);
            f3 += s_e[wv][t + 3] * bf2f(yb[(size_t)(j0 + t + 3) * NCP + lane]);
        }
        for (; t < cnt; ++t)
            f0 += s_e[wv][t] * bf2f(yb[(size_t)(j0 + t) * NCP + lane]);
        facc = facc * sc + ((f0 + f1) + (f2 + f3));
        m = nm;
    }
    if (lane < NC) {
        const float inv = (den == 0.f) ? 0.f : 1.f / den;   // empty bag -> bias
        out[(size_t)bag * NC + lane] = facc * inv + bias[lane];
    }
}

extern "C" void kernel_launch(void* const* d_in, const int* in_sizes, int n_in,
                              void* d_out, int out_size, void* d_ws, size_t ws_size,
                              hipStream_t stream)
{
    const float* x     = (const float*)d_in[0];
    const int*   label = (const int*)  d_in[1];
    const int*   seg   = (const int*)  d_in[2];
    const float* w     = (const float*)d_in[3];
    const float* bias  = (const float*)d_in[4];
    float*       out   = (float*)d_out;

    const int N = in_sizes[0] / DN;     // 131072
    const int B = out_size / NC;        // 16384

    unsigned short* wb   = (unsigned short*)d_ws;                    //  96 KB @ 0
    int*            offs = (int*)((char*)d_ws + 131072);             //  64 KB
    float*          att  = (float*)((char*)d_ws + 1048576);          // 512 KB
    unsigned short* yb   = (unsigned short*)((char*)d_ws + 2097152); // 16.8 MB

    hipLaunchKernelGGL(prep_kernel, dim3(192 + (N + 255) / 256), dim3(256), 0, stream,
                       w, seg, wb, offs, N, B);
    hipLaunchKernelGGL(gemm_y4, dim3(N / MB), dim3(256), 0, stream,
                       x, label, wb, yb, att);
    hipLaunchKernelGGL(pool_kernel, dim3((B + 3) / 4), dim3(256), 0, stream,
                       yb, att, offs, bias, out, B);
}

// Round 10
// 110.442 us; speedup vs baseline: 1.0682x; 1.0682x over previous
//
#include <hip/hip_runtime.h>
#include <math.h>

#define DN   768
#define NC   53
#define NCP  64        // classes padded for MFMA
#define NKC  6         // K chunks of 128 f32
#define MBLK 64        // rows per block (16 per wave)

typedef __attribute__((ext_vector_type(8))) __bf16 bf16x8;
typedef __attribute__((ext_vector_type(8))) short short8v;
typedef __attribute__((ext_vector_type(4))) float f32x4;

// f32 -> bf16 bits, round-to-nearest-even
static __device__ __forceinline__ unsigned short f2bf(float f) {
    unsigned int u = __builtin_bit_cast(unsigned int, f);
    u = (u + 0x7FFFu + ((u >> 16) & 1u)) >> 16;
    return (unsigned short)u;
}
static __device__ __forceinline__ float bf2f(unsigned short h) {
    unsigned int u = ((unsigned int)h) << 16;
    return __builtin_bit_cast(float, u);
}

#define GLOAD16(gptr, lptr)                                        \
    __builtin_amdgcn_global_load_lds(                              \
        (const __attribute__((address_space(1))) void*)(gptr),     \
        (__attribute__((address_space(3))) void*)(lptr), 16, 0, 0)

// ---- k0 (merged): blocks 0..191 -> wb fragment-major; 192.. -> offs ---------
__global__ void prep_kernel(const float* __restrict__ w,
                            const int*   __restrict__ seg,
                            unsigned short* __restrict__ wb,
                            int* __restrict__ offs,
                            int N, int B) {
    const int bid = blockIdx.x;
    if (bid < 192) {
        int i = bid * 256 + threadIdx.x;          // covers 24*4*64*8 = 49152
        const int e    = i & 7;
        const int lane = (i >> 3) & 63;
        const int ct   = (i >> 9) & 3;
        const int ks   = i >> 11;
        const int cls  = ct * 16 + (lane & 15);
        const int k    = ks * 32 + ((lane >> 4) << 3) + e;
        wb[i] = (cls < NC) ? f2bf(w[cls * DN + k]) : (unsigned short)0;
    } else {
        int i = (bid - 192) * 256 + threadIdx.x;
        if (i >= N) return;
        int cur  = seg[i];
        int prev = (i == 0) ? -1 : seg[i - 1];
        for (int b = prev + 1; b <= cur; ++b) offs[b] = i;
        if (i == N - 1)
            for (int b = cur + 1; b <= B; ++b) offs[b] = N;
    }
}

// ---- k1: Y_bf16[N][64] = bf16(X) @ bf16(W)^T via gl_lds-staged A ------------
// 4 waves/block; wave = 16 rows x 64 cols, wave-PRIVATE staging double-buffer
// (no __syncthreads anywhere). Counted vmcnt keeps next chunk's 24 loads in
// flight across the wait. LDS reads XOR-swizzled; inverse swizzle applied to
// the global source address (gl_lds dest must stay linear).
__global__ __launch_bounds__(256) void gemm_y5(
    const float* __restrict__ x,
    const int*   __restrict__ label,
    const unsigned short* __restrict__ wb,
    unsigned short* __restrict__ yb,   // [N][64] bf16
    float* __restrict__ att)           // [N]
{
    __shared__ float          xs[2][4][16][128];   // 64 KB: [buf][wave][row][k]
    __shared__ unsigned short yt[4][16][66];       // 8.25 KB: att-gather tile

    const int lane = threadIdx.x & 63;
    const int wv   = threadIdx.x >> 6;
    const int r16  = lane & 15;
    const int kg   = lane >> 4;                    // 0..3
    const long row0w = (long)blockIdx.x * MBLK + wv * 16;

    f32x4 acc[4];
    #pragma unroll
    for (int ct = 0; ct < 4; ++ct) acc[ct] = (f32x4){0.f, 0.f, 0.f, 0.f};

    // staging geometry (per wave, per chunk: 8 insts x 1KB = 16 rows x 512B)
    const int srowp = lane >> 5;                   // +2i covers rows 0..15
    const int sgs   = lane & 31;                   // 16B-granule slot in row
    char* const xsb = (char*)xs;

    // B fragments: register ping-pong (issued BEFORE stage so in-order vmcnt
    // retirement of lb never waits on the younger gl_lds stream)
    short8v lb[2][4][4];

#define ISSUE_LB(buf, ch)                                                      \
    {                                                                          \
        _Pragma("unroll")                                                      \
        for (int ks = 0; ks < 4; ++ks)                                         \
            _Pragma("unroll")                                                  \
            for (int ct = 0; ct < 4; ++ct)                                     \
                lb[buf][ks][ct] = *(const short8v*)(                           \
                    wb + ((((ch) * 4 + ks) * 4 + ct) * 64 + lane) * 8);        \
    }

#define STAGE(buf, ch)                                                         \
    {                                                                          \
        _Pragma("unroll")                                                      \
        for (int i = 0; i < 8; ++i) {                                          \
            const int rl = 2 * i + srowp;                                      \
            const int gx = sgs ^ (rl & 7);         /* inverse swizzle on src */\
            const float* sp = x + (row0w + rl) * (long)DN + (ch) * 128 + gx * 4;\
            char* lp = xsb + (buf) * 32768 + wv * 8192 + i * 1024; /* uniform */\
            GLOAD16(sp, lp);                                                   \
        }                                                                      \
    }

    ISSUE_LB(0, 0)
    STAGE(0, 0)

    #pragma unroll
    for (int ch = 0; ch < NKC; ++ch) {
        const int cur = ch & 1, nxt = cur ^ 1;
        if (ch + 1 < NKC) {
            ISSUE_LB(nxt, ch + 1)
            STAGE(nxt, ch + 1)
            // wait: stage(ch) done; lb(ch+1)16 + stage(ch+1)8 stay in flight
            asm volatile("s_waitcnt vmcnt(24)" ::: "memory");
        } else {
            asm volatile("s_waitcnt vmcnt(0)" ::: "memory");
        }
        // compute chunk ch: 4 k-steps of 32
        #pragma unroll
        for (int ks = 0; ks < 4; ++ks) {
            // A-frag: 2 x ds_read_b128, swizzled slots (row r16, granules
            // (ks*8+kg*2+e) ^ (r16&7)) -> 8 consecutive k values as f32
            const char* base = xsb + cur * 32768 + wv * 8192 + r16 * 512;
            const int g0 = ks * 8 + kg * 2;
            const float4 u0 = *(const float4*)(base + ((g0    ) ^ (r16 & 7)) * 16);
            const float4 u1 = *(const float4*)(base + ((g0 + 1) ^ (r16 & 7)) * 16);
            bf16x8 a8;
            a8[0] = (__bf16)u0.x; a8[1] = (__bf16)u0.y;
            a8[2] = (__bf16)u0.z; a8[3] = (__bf16)u0.w;
            a8[4] = (__bf16)u1.x; a8[5] = (__bf16)u1.y;
            a8[6] = (__bf16)u1.z; a8[7] = (__bf16)u1.w;
            #pragma unroll
            for (int ct = 0; ct < 4; ++ct)
                acc[ct] = __builtin_amdgcn_mfma_f32_16x16x32_bf16(
                    a8, __builtin_bit_cast(bf16x8, lb[cur][ks][ct]), acc[ct], 0, 0, 0);
        }
    }

#undef ISSUE_LB
#undef STAGE

    // Epilogue. C/D: col = ct*16 + r16 (class), row = kg*4 + r (0..15).
    #pragma unroll
    for (int ct = 0; ct < 4; ++ct)
        #pragma unroll
        for (int r = 0; r < 4; ++r) {
            const int   rl = kg * 4 + r;
            const float v  = acc[ct][r];
            yb[(row0w + rl) * NCP + ct * 16 + r16] = f2bf(v);
            yt[wv][rl][ct * 16 + r16] = f2bf(v);
        }
    // same-wave LDS RAW (compiler inserts lgkmcnt); no barrier needed
    if (lane < 16) {
        const long grow = row0w + lane;
        const int  lab  = label[grow];
        att[grow] = bf2f(yt[wv][lane][lab]);
    }
}

// ---- k2: per-bag softmax pooling: att coalesced + bf16 y rows ---------------
__global__ __launch_bounds__(256) void pool_kernel(
    const unsigned short* __restrict__ yb,
    const float* __restrict__ att,
    const int*   __restrict__ offs,
    const float* __restrict__ bias,
    float*       __restrict__ out,
    int Btot)
{
    __shared__ float s_e[4][64];
    const int wv   = threadIdx.x >> 6;
    const int lane = threadIdx.x & 63;
    const int bag  = blockIdx.x * 4 + wv;
    if (bag >= Btot) return;
    const int s = offs[bag], e = offs[bag + 1];

    float m = -INFINITY, den = 0.f, facc = 0.f;
    for (int j0 = s; j0 < e; j0 += 64) {
        const int j = j0 + lane;
        float a = (j < e) ? att[j] : -INFINITY;          // coalesced stream
        float cm = a;
        #pragma unroll
        for (int off = 1; off < 64; off <<= 1) cm = fmaxf(cm, __shfl_xor(cm, off));
        const float nm = fmaxf(m, cm);
        const float sc = __expf(m - nm);                 // first iter: exp(-inf)=0
        const float ej = (j < e) ? __expf(a - nm) : 0.f;
        float cd = ej;
        #pragma unroll
        for (int off = 1; off < 64; off <<= 1) cd += __shfl_xor(cd, off);
        den = den * sc + cd;
        s_e[wv][lane] = ej;                              // same-wave LDS broadcast
        const int cnt = min(64, e - j0);
        float f0 = 0.f, f1 = 0.f, f2 = 0.f, f3 = 0.f;
        int t = 0;
        for (; t + 4 <= cnt; t += 4) {                   // 4 chains break FMA dep
            f0 += s_e[wv][t]     * bf2f(yb[(size_t)(j0 + t)     * NCP + lane]);
            f1 += s_e[wv][t + 1] * bf2f(yb[(size_t)(j0 + t + 1) * NCP + lane]);
            f2 += s_e[wv][t + 2] * bf2f(yb[(size_t)(j0 + t + 2) * NCP + lane]);
            f3 += s_e[wv][t + 3] * bf2f(yb[(size_t)(j0 + t + 3) * NCP + lane]);
        }
        for (; t < cnt; ++t)
            f0 += s_e[wv][t] * bf2f(yb[(size_t)(j0 + t) * NCP + lane]);
        facc = facc * sc + ((f0 + f1) + (f2 + f3));
        m = nm;
    }
    if (lane < NC) {
        const float inv = (den == 0.f) ? 0.f : 1.f / den;   // empty bag -> bias
        out[(size_t)bag * NC + lane] = facc * inv + bias[lane];
    }
}

extern "C" void kernel_launch(void* const* d_in, const int* in_sizes, int n_in,
                              void* d_out, int out_size, void* d_ws, size_t ws_size,
                              hipStream_t stream)
{
    const float* x     = (const float*)d_in[0];
    const int*   label = (const int*)  d_in[1];
    const int*   seg   = (const int*)  d_in[2];
    const float* w     = (const float*)d_in[3];
    const float* bias  = (const float*)d_in[4];
    float*       out   = (float*)d_out;

    const int N = in_sizes[0] / DN;     // 131072
    const int B = out_size / NC;        // 16384

    unsigned short* wb   = (unsigned short*)d_ws;                    //  96 KB @ 0
    int*            offs = (int*)((char*)d_ws + 131072);             //  64 KB
    float*          att  = (float*)((char*)d_ws + 1048576);          // 512 KB
    unsigned short* yb   = (unsigned short*)((char*)d_ws + 2097152); // 16.8 MB

    hipLaunchKernelGGL(prep_kernel, dim3(192 + (N + 255) / 256), dim3(256), 0, stream,
                       w, seg, wb, offs, N, B);
    hipLaunchKernelGGL(gemm_y5, dim3(N / MBLK), dim3(256), 0, stream,
                       x, label, wb, yb, att);
    hipLaunchKernelGGL(pool_kernel, dim3((B + 3) / 4), dim3(256), 0, stream,
                       yb, att, offs, bias, out, B);
}